// Round 1
// baseline (690.177 us; speedup 1.0000x reference)
//
#include <hip/hip_runtime.h>
#include <math.h>

#define T_STEPS 3
#define N_NODES 100000
#define N_EDGES 1600000
#define D 64

// ---------------------------------------------------------------------------
// ws layout (floats):
//   [0,192)           colsum[3][64]          (memset 0 each call)
//   [192,300192)      acc[3][N]              (memset 0 each call)
//   [300192,600192)   deg[3][N]              (memset 0 each call)
//   [600192,600384)   v[3][64]
//   [600384,900384)   s[3][N]
// ---------------------------------------------------------------------------

// Pass 1: column sums of x_t over nodes, for all t in one pass over x.
__global__ __launch_bounds__(256) void colsum_kernel(const float* __restrict__ x,
                                                     float* __restrict__ colsum) {
    const int t = blockIdx.y;
    const int tid = threadIdx.x;
    const int q = tid & 15;   // float4 index within a row (0..15)
    const int g = tid >> 4;   // row group (0..15)
    const float4* xt = (const float4*)(x + (size_t)t * N_NODES * D);
    const int base = blockIdx.x * 128;   // 128 rows per block
    float sx = 0.f, sy = 0.f, sz = 0.f, sw = 0.f;
#pragma unroll
    for (int it = 0; it < 8; ++it) {
        const int r = base + g + 16 * it;
        if (r < N_NODES) {
            const float4 vv = xt[(size_t)r * 16 + q];
            sx += vv.x; sy += vv.y; sz += vv.z; sw += vv.w;
        }
    }
    __shared__ float red[16][64];
    red[g][q * 4 + 0] = sx;
    red[g][q * 4 + 1] = sy;
    red[g][q * 4 + 2] = sz;
    red[g][q * 4 + 3] = sw;
    __syncthreads();
    if (tid < 64) {
        float s = 0.f;
#pragma unroll
        for (int gg = 0; gg < 16; ++gg) s += red[gg][tid];
        atomicAdd(&colsum[t * 64 + tid], s);
    }
}

__device__ __forceinline__ float sigmoidf_(float v) {
    return 1.f / (1.f + expf(-v));
}

// Single-block kernel: whole 3-step MatGRU weight-evolution chain.
// Produces v[t] = w_t @ Wo for every step and writes w_final.
__global__ __launch_bounds__(256) void gru_kernel(
    const float* __restrict__ colsum, const float* __restrict__ iw,
    const float* __restrict__ Wz, const float* __restrict__ bz,
    const float* __restrict__ Wr, const float* __restrict__ br,
    const float* __restrict__ Wh, const float* __restrict__ bh,
    const float* __restrict__ Wp, const float* __restrict__ bp,
    const float* __restrict__ Wo,
    float* __restrict__ v_out, float* __restrict__ w_final) {
    // wT[k*64+i] = w[i][k]  (transposed so float4 over i works)
    __shared__ float wT[4096];
    __shared__ float B0[4096];   // WzB, then reused as rwT
    __shared__ float B1[4096];   // WrB, then reused as WhB
    __shared__ float sml[384];   // mean | ctx | cz | cr | ch | wo
    float* mean_s = sml;
    float* ctx_s  = sml + 64;
    float* cz_s   = sml + 128;
    float* cr_s   = sml + 192;
    float* ch_s   = sml + 256;
    float* wo_s   = sml + 320;

    const int tid = threadIdx.x;
    for (int idx = tid; idx < 4096; idx += 256) {
        const int i = idx >> 6, k = idx & 63;
        wT[(k << 6) | i] = iw[idx];
    }
    if (tid < 64) wo_s[tid] = Wo[tid];
    __syncthreads();

    const int j0 = (tid & 15) << 2;
    const int i0 = (tid >> 4) << 2;

    for (int t = 0; t < T_STEPS; ++t) {
        // --- mean + load WzB/WrB (bottom halves) ---
        if (tid < 64) mean_s[tid] = colsum[t * 64 + tid] * (1.0f / (float)N_NODES);
        for (int idx = tid; idx < 4096; idx += 256) {
            const int k = idx >> 6, j = idx & 63;
            B0[idx] = Wz[(64 + k) * 64 + j];
            B1[idx] = Wr[(64 + k) * 64 + j];
        }
        __syncthreads();
        // --- ctx = mean @ Wp + bp ---
        if (tid < 64) {
            float c = bp[tid];
            for (int k = 0; k < 64; ++k) c = fmaf(mean_s[k], Wp[k * 64 + tid], c);
            ctx_s[tid] = c;
        }
        __syncthreads();
        // --- ctx contributions through top halves of Wz/Wr/Wh ---
        if (tid < 64) {
            float az = bz[tid], ar = br[tid], ah = bh[tid];
            for (int k = 0; k < 64; ++k) {
                const float c = ctx_s[k];
                az = fmaf(c, Wz[k * 64 + tid], az);
                ar = fmaf(c, Wr[k * 64 + tid], ar);
                ah = fmaf(c, Wh[k * 64 + tid], ah);
            }
            cz_s[tid] = az; cr_s[tid] = ar; ch_s[tid] = ah;
        }
        __syncthreads();
        // --- z and r: [64,64] = w @ WzB / w @ WrB ---
        float accZ[4][4] = {{0.f}}, accR[4][4] = {{0.f}};
        for (int k = 0; k < 64; ++k) {
            const float4 wv = *(const float4*)&wT[(k << 6) + i0];
            const float4 zj = *(const float4*)&B0[(k << 6) + j0];
            const float4 rj = *(const float4*)&B1[(k << 6) + j0];
            const float wa[4] = {wv.x, wv.y, wv.z, wv.w};
            const float zb[4] = {zj.x, zj.y, zj.z, zj.w};
            const float rb[4] = {rj.x, rj.y, rj.z, rj.w};
#pragma unroll
            for (int a = 0; a < 4; ++a)
#pragma unroll
                for (int b = 0; b < 4; ++b) {
                    accZ[a][b] = fmaf(wa[a], zb[b], accZ[a][b]);
                    accR[a][b] = fmaf(wa[a], rb[b], accR[a][b]);
                }
        }
        float zv[4][4], rv[4][4];
#pragma unroll
        for (int a = 0; a < 4; ++a)
#pragma unroll
            for (int b = 0; b < 4; ++b) {
                zv[a][b] = sigmoidf_(accZ[a][b] + cz_s[j0 + b]);
                rv[a][b] = sigmoidf_(accR[a][b] + cr_s[j0 + b]);
            }
        __syncthreads();   // everyone done reading wT/B0/B1 for z/r
        // --- build rwT = (r*w)^T into B0, load WhB into B1 ---
#pragma unroll
        for (int a = 0; a < 4; ++a)
#pragma unroll
            for (int b = 0; b < 4; ++b) {
                const int o = ((j0 + b) << 6) + (i0 + a);
                B0[o] = rv[a][b] * wT[o];
            }
        for (int idx = tid; idx < 4096; idx += 256) {
            const int k = idx >> 6, j = idx & 63;
            B1[idx] = Wh[(64 + k) * 64 + j];
        }
        __syncthreads();
        // --- h_tilde matmul: (r*w) @ WhB ---
        float accH[4][4] = {{0.f}};
        for (int k = 0; k < 64; ++k) {
            const float4 hv = *(const float4*)&B0[(k << 6) + i0];
            const float4 hj = *(const float4*)&B1[(k << 6) + j0];
            const float ha[4] = {hv.x, hv.y, hv.z, hv.w};
            const float hb[4] = {hj.x, hj.y, hj.z, hj.w};
#pragma unroll
            for (int a = 0; a < 4; ++a)
#pragma unroll
                for (int b = 0; b < 4; ++b)
                    accH[a][b] = fmaf(ha[a], hb[b], accH[a][b]);
        }
        // --- w_new = z*w + (1-z)*h_tilde ; v = w_new @ Wo ---
        float vpart[4] = {0.f, 0.f, 0.f, 0.f};
#pragma unroll
        for (int a = 0; a < 4; ++a)
#pragma unroll
            for (int b = 0; b < 4; ++b) {
                const int o = ((j0 + b) << 6) + (i0 + a);
                const float h = tanhf(accH[a][b] + ch_s[j0 + b]);
                const float z = zv[a][b];
                const float wn = z * wT[o] + (1.f - z) * h;
                wT[o] = wn;                       // disjoint per-thread tiles
                vpart[a] = fmaf(wn, wo_s[j0 + b], vpart[a]);
            }
#pragma unroll
        for (int a = 0; a < 4; ++a) {
            float vp = vpart[a];
            vp += __shfl_xor(vp, 1);
            vp += __shfl_xor(vp, 2);
            vp += __shfl_xor(vp, 4);
            vp += __shfl_xor(vp, 8);
            if ((tid & 15) == 0) v_out[t * 64 + i0 + a] = vp;
        }
        __syncthreads();
    }
    // w_final[i][j] = wT[j][i]
    for (int idx = tid; idx < 4096; idx += 256) {
        const int i = idx >> 6, j = idx & 63;
        w_final[idx] = wT[(j << 6) | i];
    }
}

// s_t[n] = x_t[n] . v_t   (4 lanes per row)
__global__ __launch_bounds__(256) void smatvec_kernel(const float* __restrict__ x,
                                                      const float* __restrict__ v,
                                                      float* __restrict__ s) {
    const int t = blockIdx.y;
    const int tid = threadIdx.x;
    const int l4 = tid & 3;
    const int rloc = tid >> 2;   // 0..63
    __shared__ float vs[64];
    if (tid < 64) vs[tid] = v[t * 64 + tid];
    __syncthreads();
    const int row = blockIdx.x * 64 + rloc;
    if (row < N_NODES) {
        const float4* xr = (const float4*)(x + ((size_t)t * N_NODES + row) * D);
        float acc = 0.f;
#pragma unroll
        for (int i = 0; i < 4; ++i) {
            const int c = i * 4 + l4;     // float4 chunk 0..15 of the row
            const float4 xv = xr[c];
            acc += xv.x * vs[c * 4 + 0] + xv.y * vs[c * 4 + 1] +
                   xv.z * vs[c * 4 + 2] + xv.w * vs[c * 4 + 3];
        }
        acc += __shfl_xor(acc, 1);
        acc += __shfl_xor(acc, 2);
        if (l4 == 0) s[(size_t)t * N_NODES + row] = acc;
    }
}

// Scatter: acc[dst] += s[src]; deg[dst] += 1
__global__ __launch_bounds__(256) void edge_kernel(const int* __restrict__ src,
                                                   const int* __restrict__ dst,
                                                   const float* __restrict__ s,
                                                   float* __restrict__ acc,
                                                   float* __restrict__ deg) {
    const int t = blockIdx.y;
    const int e4 = blockIdx.x * 256 + threadIdx.x;   // int4 index
    if (e4 * 4 >= N_EDGES) return;
    const int4* sp = (const int4*)(src + (size_t)t * N_EDGES);
    const int4* dp = (const int4*)(dst + (size_t)t * N_EDGES);
    const float* st = s + (size_t)t * N_NODES;
    float* at = acc + (size_t)t * N_NODES;
    float* dg = deg + (size_t)t * N_NODES;
    const int4 s4 = sp[e4];
    const int4 d4 = dp[e4];
    const float v0 = st[s4.x], v1 = st[s4.y], v2 = st[s4.z], v3 = st[s4.w];
    atomicAdd(&at[d4.x], v0); atomicAdd(&dg[d4.x], 1.0f);
    atomicAdd(&at[d4.y], v1); atomicAdd(&dg[d4.y], 1.0f);
    atomicAdd(&at[d4.z], v2); atomicAdd(&dg[d4.z], 1.0f);
    atomicAdd(&at[d4.w], v3); atomicAdd(&dg[d4.w], 1.0f);
}

__global__ __launch_bounds__(256) void out_kernel(const float* __restrict__ acc,
                                                  const float* __restrict__ deg,
                                                  const float* __restrict__ bo,
                                                  float* __restrict__ out) {
    const int i = blockIdx.x * 256 + threadIdx.x;
    if (i < T_STEPS * N_NODES) {
        out[i] = bo[0] + acc[i] / fmaxf(deg[i], 1.0f);
    }
}

extern "C" void kernel_launch(void* const* d_in, const int* in_sizes, int n_in,
                              void* d_out, int out_size, void* d_ws, size_t ws_size,
                              hipStream_t stream) {
    const float* x  = (const float*)d_in[0];
    const int* src  = (const int*)d_in[1];
    const int* dst  = (const int*)d_in[2];
    const float* iw = (const float*)d_in[3];
    const float* Wz = (const float*)d_in[4];
    const float* bz = (const float*)d_in[5];
    const float* Wr = (const float*)d_in[6];
    const float* br = (const float*)d_in[7];
    const float* Wh = (const float*)d_in[8];
    const float* bh = (const float*)d_in[9];
    const float* Wp = (const float*)d_in[10];
    const float* bp = (const float*)d_in[11];
    const float* Wo = (const float*)d_in[12];
    const float* bo = (const float*)d_in[13];
    float* out = (float*)d_out;   // [3*N outs][64*64 w_final]
    float* ws  = (float*)d_ws;

    float* colsum = ws;            // 192
    float* accb   = ws + 192;      // 300000
    float* degb   = ws + 300192;   // 300000
    float* vbuf   = ws + 600192;   // 192
    float* sbuf   = ws + 600384;   // 300000

    // zero colsum/acc/deg (atomic targets) every call
    hipMemsetAsync(ws, 0, (size_t)600192 * sizeof(float), stream);

    colsum_kernel<<<dim3(782, 3), 256, 0, stream>>>(x, colsum);
    gru_kernel<<<1, 256, 0, stream>>>(colsum, iw, Wz, bz, Wr, br, Wh, bh,
                                      Wp, bp, Wo, vbuf, out + (size_t)T_STEPS * N_NODES);
    smatvec_kernel<<<dim3(1563, 3), 256, 0, stream>>>(x, vbuf, sbuf);
    edge_kernel<<<dim3(1563, 3), 256, 0, stream>>>(src, dst, sbuf, accb, degb);
    out_kernel<<<1172, 256, 0, stream>>>(accb, degb, bo, out);
}

// Round 2
// 427.498 us; speedup vs baseline: 1.6145x; 1.6145x over previous
//
#include <hip/hip_runtime.h>
#include <math.h>

#define T_STEPS 3
#define N_NODES 100000
#define N_EDGES 1600000
#define D 64

// ---------------------------------------------------------------------------
// ws layout (floats):
//   [0,192)           colsum[3][64]            (memset 0 each call)
//   [192,600192)      packed[3][N] as uint64   (memset 0 each call)
//                     packed = sum over incoming edges of (2^41 + s*2^20)
//   [600192,600384)   v[3][64]
//   [600384,900384)   s[3][N]
// ---------------------------------------------------------------------------

#define PACK_SCALE 1048576.0f          // 2^20
#define PACK_INV   (1.0f / 1048576.0f)

// Pass 1: column sums of x_t over nodes, for all t in one pass over x.
__global__ __launch_bounds__(256) void colsum_kernel(const float* __restrict__ x,
                                                     float* __restrict__ colsum) {
    const int t = blockIdx.y;
    const int tid = threadIdx.x;
    const int q = tid & 15;   // float4 index within a row (0..15)
    const int g = tid >> 4;   // row group (0..15)
    const float4* xt = (const float4*)(x + (size_t)t * N_NODES * D);
    const int base = blockIdx.x * 128;   // 128 rows per block
    float sx = 0.f, sy = 0.f, sz = 0.f, sw = 0.f;
#pragma unroll
    for (int it = 0; it < 8; ++it) {
        const int r = base + g + 16 * it;
        if (r < N_NODES) {
            const float4 vv = xt[(size_t)r * 16 + q];
            sx += vv.x; sy += vv.y; sz += vv.z; sw += vv.w;
        }
    }
    __shared__ float red[16][64];
    red[g][q * 4 + 0] = sx;
    red[g][q * 4 + 1] = sy;
    red[g][q * 4 + 2] = sz;
    red[g][q * 4 + 3] = sw;
    __syncthreads();
    if (tid < 64) {
        float s = 0.f;
#pragma unroll
        for (int gg = 0; gg < 16; ++gg) s += red[gg][tid];
        atomicAdd(&colsum[t * 64 + tid], s);
    }
}

__device__ __forceinline__ float sigmoidf_(float v) {
    return 1.f / (1.f + expf(-v));
}

// Single-block kernel: whole 3-step MatGRU weight-evolution chain.
// Produces v[t] = w_t @ Wo for every step and writes w_final.
__global__ __launch_bounds__(256) void gru_kernel(
    const float* __restrict__ colsum, const float* __restrict__ iw,
    const float* __restrict__ Wz, const float* __restrict__ bz,
    const float* __restrict__ Wr, const float* __restrict__ br,
    const float* __restrict__ Wh, const float* __restrict__ bh,
    const float* __restrict__ Wp, const float* __restrict__ bp,
    const float* __restrict__ Wo,
    float* __restrict__ v_out, float* __restrict__ w_final) {
    // wT[k*64+i] = w[i][k]  (transposed so float4 over i works)
    __shared__ float wT[4096];
    __shared__ float B0[4096];   // WzB, then reused as rwT
    __shared__ float B1[4096];   // WrB, then reused as WhB
    __shared__ float sml[384];   // mean | ctx | cz | cr | ch | wo
    float* mean_s = sml;
    float* ctx_s  = sml + 64;
    float* cz_s   = sml + 128;
    float* cr_s   = sml + 192;
    float* ch_s   = sml + 256;
    float* wo_s   = sml + 320;

    const int tid = threadIdx.x;
    for (int idx = tid; idx < 4096; idx += 256) {
        const int i = idx >> 6, k = idx & 63;
        wT[(k << 6) | i] = iw[idx];
    }
    if (tid < 64) wo_s[tid] = Wo[tid];
    __syncthreads();

    const int j0 = (tid & 15) << 2;
    const int i0 = (tid >> 4) << 2;

    for (int t = 0; t < T_STEPS; ++t) {
        // --- mean + load WzB/WrB (bottom halves) ---
        if (tid < 64) mean_s[tid] = colsum[t * 64 + tid] * (1.0f / (float)N_NODES);
        for (int idx = tid; idx < 4096; idx += 256) {
            const int k = idx >> 6, j = idx & 63;
            B0[idx] = Wz[(64 + k) * 64 + j];
            B1[idx] = Wr[(64 + k) * 64 + j];
        }
        __syncthreads();
        // --- ctx = mean @ Wp + bp ---
        if (tid < 64) {
            float c = bp[tid];
            for (int k = 0; k < 64; ++k) c = fmaf(mean_s[k], Wp[k * 64 + tid], c);
            ctx_s[tid] = c;
        }
        __syncthreads();
        // --- ctx contributions through top halves of Wz/Wr/Wh ---
        if (tid < 64) {
            float az = bz[tid], ar = br[tid], ah = bh[tid];
            for (int k = 0; k < 64; ++k) {
                const float c = ctx_s[k];
                az = fmaf(c, Wz[k * 64 + tid], az);
                ar = fmaf(c, Wr[k * 64 + tid], ar);
                ah = fmaf(c, Wh[k * 64 + tid], ah);
            }
            cz_s[tid] = az; cr_s[tid] = ar; ch_s[tid] = ah;
        }
        __syncthreads();
        // --- z and r: [64,64] = w @ WzB / w @ WrB ---
        float accZ[4][4] = {{0.f}}, accR[4][4] = {{0.f}};
        for (int k = 0; k < 64; ++k) {
            const float4 wv = *(const float4*)&wT[(k << 6) + i0];
            const float4 zj = *(const float4*)&B0[(k << 6) + j0];
            const float4 rj = *(const float4*)&B1[(k << 6) + j0];
            const float wa[4] = {wv.x, wv.y, wv.z, wv.w};
            const float zb[4] = {zj.x, zj.y, zj.z, zj.w};
            const float rb[4] = {rj.x, rj.y, rj.z, rj.w};
#pragma unroll
            for (int a = 0; a < 4; ++a)
#pragma unroll
                for (int b = 0; b < 4; ++b) {
                    accZ[a][b] = fmaf(wa[a], zb[b], accZ[a][b]);
                    accR[a][b] = fmaf(wa[a], rb[b], accR[a][b]);
                }
        }
        float zv[4][4], rv[4][4];
#pragma unroll
        for (int a = 0; a < 4; ++a)
#pragma unroll
            for (int b = 0; b < 4; ++b) {
                zv[a][b] = sigmoidf_(accZ[a][b] + cz_s[j0 + b]);
                rv[a][b] = sigmoidf_(accR[a][b] + cr_s[j0 + b]);
            }
        __syncthreads();   // everyone done reading wT/B0/B1 for z/r
        // --- build rwT = (r*w)^T into B0, load WhB into B1 ---
#pragma unroll
        for (int a = 0; a < 4; ++a)
#pragma unroll
            for (int b = 0; b < 4; ++b) {
                const int o = ((j0 + b) << 6) + (i0 + a);
                B0[o] = rv[a][b] * wT[o];
            }
        for (int idx = tid; idx < 4096; idx += 256) {
            const int k = idx >> 6, j = idx & 63;
            B1[idx] = Wh[(64 + k) * 64 + j];
        }
        __syncthreads();
        // --- h_tilde matmul: (r*w) @ WhB ---
        float accH[4][4] = {{0.f}};
        for (int k = 0; k < 64; ++k) {
            const float4 hv = *(const float4*)&B0[(k << 6) + i0];
            const float4 hj = *(const float4*)&B1[(k << 6) + j0];
            const float ha[4] = {hv.x, hv.y, hv.z, hv.w};
            const float hb[4] = {hj.x, hj.y, hj.z, hj.w};
#pragma unroll
            for (int a = 0; a < 4; ++a)
#pragma unroll
                for (int b = 0; b < 4; ++b)
                    accH[a][b] = fmaf(ha[a], hb[b], accH[a][b]);
        }
        // --- w_new = z*w + (1-z)*h_tilde ; v = w_new @ Wo ---
        float vpart[4] = {0.f, 0.f, 0.f, 0.f};
#pragma unroll
        for (int a = 0; a < 4; ++a)
#pragma unroll
            for (int b = 0; b < 4; ++b) {
                const int o = ((j0 + b) << 6) + (i0 + a);
                const float h = tanhf(accH[a][b] + ch_s[j0 + b]);
                const float z = zv[a][b];
                const float wn = z * wT[o] + (1.f - z) * h;
                wT[o] = wn;                       // disjoint per-thread tiles
                vpart[a] = fmaf(wn, wo_s[j0 + b], vpart[a]);
            }
#pragma unroll
        for (int a = 0; a < 4; ++a) {
            float vp = vpart[a];
            vp += __shfl_xor(vp, 1);
            vp += __shfl_xor(vp, 2);
            vp += __shfl_xor(vp, 4);
            vp += __shfl_xor(vp, 8);
            if ((tid & 15) == 0) v_out[t * 64 + i0 + a] = vp;
        }
        __syncthreads();
    }
    // w_final[i][j] = wT[j][i]
    for (int idx = tid; idx < 4096; idx += 256) {
        const int i = idx >> 6, j = idx & 63;
        w_final[idx] = wT[(j << 6) | i];
    }
}

// s_t[n] = x_t[n] . v_t   (4 lanes per row)
__global__ __launch_bounds__(256) void smatvec_kernel(const float* __restrict__ x,
                                                      const float* __restrict__ v,
                                                      float* __restrict__ s) {
    const int t = blockIdx.y;
    const int tid = threadIdx.x;
    const int l4 = tid & 3;
    const int rloc = tid >> 2;   // 0..63
    __shared__ float vs[64];
    if (tid < 64) vs[tid] = v[t * 64 + tid];
    __syncthreads();
    const int row = blockIdx.x * 64 + rloc;
    if (row < N_NODES) {
        const float4* xr = (const float4*)(x + ((size_t)t * N_NODES + row) * D);
        float acc = 0.f;
#pragma unroll
        for (int i = 0; i < 4; ++i) {
            const int c = i * 4 + l4;     // float4 chunk 0..15 of the row
            const float4 xv = xr[c];
            acc += xv.x * vs[c * 4 + 0] + xv.y * vs[c * 4 + 1] +
                   xv.z * vs[c * 4 + 2] + xv.w * vs[c * 4 + 3];
        }
        acc += __shfl_xor(acc, 1);
        acc += __shfl_xor(acc, 2);
        if (l4 == 0) s[(size_t)t * N_NODES + row] = acc;
    }
}

// Scatter: packed[dst] += 2^41 + round(s[src]*2^20)   (one 64-bit atomic/edge)
__global__ __launch_bounds__(256) void edge_kernel(const int* __restrict__ src,
                                                   const int* __restrict__ dst,
                                                   const float* __restrict__ s,
                                                   unsigned long long* __restrict__ packed) {
    const int t = blockIdx.y;
    const int e4 = blockIdx.x * 256 + threadIdx.x;   // int4 index
    if (e4 * 4 >= N_EDGES) return;
    const int4* sp = (const int4*)(src + (size_t)t * N_EDGES);
    const int4* dp = (const int4*)(dst + (size_t)t * N_EDGES);
    const float* st = s + (size_t)t * N_NODES;
    unsigned long long* pk = packed + (size_t)t * N_NODES;
    const int4 s4 = sp[e4];
    const int4 d4 = dp[e4];
    const float v0 = st[s4.x], v1 = st[s4.y], v2 = st[s4.z], v3 = st[s4.w];
    const unsigned long long base = 1ULL << 41;
    atomicAdd(&pk[d4.x], base + (unsigned long long)(long long)llrintf(v0 * PACK_SCALE));
    atomicAdd(&pk[d4.y], base + (unsigned long long)(long long)llrintf(v1 * PACK_SCALE));
    atomicAdd(&pk[d4.z], base + (unsigned long long)(long long)llrintf(v2 * PACK_SCALE));
    atomicAdd(&pk[d4.w], base + (unsigned long long)(long long)llrintf(v3 * PACK_SCALE));
}

// Unpack: deg = round(total / 2^41), acc = (total - deg*2^41) * 2^-20
__global__ __launch_bounds__(256) void out_kernel(const unsigned long long* __restrict__ packed,
                                                  const float* __restrict__ bo,
                                                  float* __restrict__ out) {
    const int i = blockIdx.x * 256 + threadIdx.x;
    if (i < T_STEPS * N_NODES) {
        const unsigned long long tot = packed[i];
        const unsigned long long deg = (tot + (1ULL << 40)) >> 41;
        const long long rem = (long long)(tot - (deg << 41));
        const float acc = (float)rem * PACK_INV;
        out[i] = bo[0] + acc / fmaxf((float)deg, 1.0f);
    }
}

extern "C" void kernel_launch(void* const* d_in, const int* in_sizes, int n_in,
                              void* d_out, int out_size, void* d_ws, size_t ws_size,
                              hipStream_t stream) {
    const float* x  = (const float*)d_in[0];
    const int* src  = (const int*)d_in[1];
    const int* dst  = (const int*)d_in[2];
    const float* iw = (const float*)d_in[3];
    const float* Wz = (const float*)d_in[4];
    const float* bz = (const float*)d_in[5];
    const float* Wr = (const float*)d_in[6];
    const float* br = (const float*)d_in[7];
    const float* Wh = (const float*)d_in[8];
    const float* bh = (const float*)d_in[9];
    const float* Wp = (const float*)d_in[10];
    const float* bp = (const float*)d_in[11];
    const float* Wo = (const float*)d_in[12];
    const float* bo = (const float*)d_in[13];
    float* out = (float*)d_out;   // [3*N outs][64*64 w_final]
    float* ws  = (float*)d_ws;

    float* colsum = ws;                                        // 192 floats
    unsigned long long* packed = (unsigned long long*)(ws + 192);  // 300000 u64
    float* vbuf   = ws + 600192;                               // 192
    float* sbuf   = ws + 600384;                               // 300000

    // zero colsum + packed (atomic targets) every call
    hipMemsetAsync(ws, 0, (size_t)600192 * sizeof(float), stream);

    colsum_kernel<<<dim3(782, 3), 256, 0, stream>>>(x, colsum);
    gru_kernel<<<1, 256, 0, stream>>>(colsum, iw, Wz, bz, Wr, br, Wh, bh,
                                      Wp, bp, Wo, vbuf, out + (size_t)T_STEPS * N_NODES);
    smatvec_kernel<<<dim3(1563, 3), 256, 0, stream>>>(x, vbuf, sbuf);
    edge_kernel<<<dim3(1563, 3), 256, 0, stream>>>(src, dst, sbuf, packed);
    out_kernel<<<1172, 256, 0, stream>>>(packed, bo, out);
}

// Round 3
// 280.863 us; speedup vs baseline: 2.4573x; 1.5221x over previous
//
#include <hip/hip_runtime.h>
#include <math.h>

#define T_STEPS 3
#define N_NODES 100000
#define N_EDGES 1600000
#define N_E4    (N_EDGES / 4)
#define D 64

// Bucketed-scatter parameters
#define BKT_BITS 9
#define BKT_SIZE 512
#define NBKT 196            // ceil(100000/512)
#define QSCALE 65536.0f     // 2^16
#define QINV   (1.0f / 65536.0f)

// Fallback (packed global atomic) parameters
#define PACK_SCALE 1048576.0f
#define PACK_INV   (1.0f / 1048576.0f)

// ---------------------------------------------------------------------------
// FAST ws layout (float offsets):
//   [0,192)            colsum[3][64]     (memset)
//   [192,384)          v[3][64]
//   [384,300384)       s[3][N]
//   [300384,301152)    hist[3][256] u32  (memset)
//   [301152,301920)    bucketStart[3][256] u32 (written by scan)
//   [301920,302688)    cursor[3][256] u32      (written by scan)
//   [302688,5102688)   recs[3][E] u32
// FALLBACK layout = round-2 layout.
// ---------------------------------------------------------------------------

__global__ __launch_bounds__(256) void colsum_kernel(const float* __restrict__ x,
                                                     float* __restrict__ colsum) {
    const int t = blockIdx.y;
    const int tid = threadIdx.x;
    const int q = tid & 15;
    const int g = tid >> 4;
    const float4* xt = (const float4*)(x + (size_t)t * N_NODES * D);
    const int base = blockIdx.x * 128;
    float sx = 0.f, sy = 0.f, sz = 0.f, sw = 0.f;
#pragma unroll
    for (int it = 0; it < 8; ++it) {
        const int r = base + g + 16 * it;
        if (r < N_NODES) {
            const float4 vv = xt[(size_t)r * 16 + q];
            sx += vv.x; sy += vv.y; sz += vv.z; sw += vv.w;
        }
    }
    __shared__ float red[16][64];
    red[g][q * 4 + 0] = sx;
    red[g][q * 4 + 1] = sy;
    red[g][q * 4 + 2] = sz;
    red[g][q * 4 + 3] = sw;
    __syncthreads();
    if (tid < 64) {
        float s = 0.f;
#pragma unroll
        for (int gg = 0; gg < 16; ++gg) s += red[gg][tid];
        atomicAdd(&colsum[t * 64 + tid], s);
    }
}

__device__ __forceinline__ float sigmoidf_(float v) {
    return 1.f / (1.f + expf(-v));
}

__global__ __launch_bounds__(256) void gru_kernel(
    const float* __restrict__ colsum, const float* __restrict__ iw,
    const float* __restrict__ Wz, const float* __restrict__ bz,
    const float* __restrict__ Wr, const float* __restrict__ br,
    const float* __restrict__ Wh, const float* __restrict__ bh,
    const float* __restrict__ Wp, const float* __restrict__ bp,
    const float* __restrict__ Wo,
    float* __restrict__ v_out, float* __restrict__ w_final) {
    __shared__ float wT[4096];
    __shared__ float B0[4096];
    __shared__ float B1[4096];
    __shared__ float sml[384];
    float* mean_s = sml;
    float* ctx_s  = sml + 64;
    float* cz_s   = sml + 128;
    float* cr_s   = sml + 192;
    float* ch_s   = sml + 256;
    float* wo_s   = sml + 320;

    const int tid = threadIdx.x;
    for (int idx = tid; idx < 4096; idx += 256) {
        const int i = idx >> 6, k = idx & 63;
        wT[(k << 6) | i] = iw[idx];
    }
    if (tid < 64) wo_s[tid] = Wo[tid];
    __syncthreads();

    const int j0 = (tid & 15) << 2;
    const int i0 = (tid >> 4) << 2;

    for (int t = 0; t < T_STEPS; ++t) {
        if (tid < 64) mean_s[tid] = colsum[t * 64 + tid] * (1.0f / (float)N_NODES);
        for (int idx = tid; idx < 4096; idx += 256) {
            const int k = idx >> 6, j = idx & 63;
            B0[idx] = Wz[(64 + k) * 64 + j];
            B1[idx] = Wr[(64 + k) * 64 + j];
        }
        __syncthreads();
        if (tid < 64) {
            float c = bp[tid];
            for (int k = 0; k < 64; ++k) c = fmaf(mean_s[k], Wp[k * 64 + tid], c);
            ctx_s[tid] = c;
        }
        __syncthreads();
        if (tid < 64) {
            float az = bz[tid], ar = br[tid], ah = bh[tid];
            for (int k = 0; k < 64; ++k) {
                const float c = ctx_s[k];
                az = fmaf(c, Wz[k * 64 + tid], az);
                ar = fmaf(c, Wr[k * 64 + tid], ar);
                ah = fmaf(c, Wh[k * 64 + tid], ah);
            }
            cz_s[tid] = az; cr_s[tid] = ar; ch_s[tid] = ah;
        }
        __syncthreads();
        float accZ[4][4] = {{0.f}}, accR[4][4] = {{0.f}};
        for (int k = 0; k < 64; ++k) {
            const float4 wv = *(const float4*)&wT[(k << 6) + i0];
            const float4 zj = *(const float4*)&B0[(k << 6) + j0];
            const float4 rj = *(const float4*)&B1[(k << 6) + j0];
            const float wa[4] = {wv.x, wv.y, wv.z, wv.w};
            const float zb[4] = {zj.x, zj.y, zj.z, zj.w};
            const float rb[4] = {rj.x, rj.y, rj.z, rj.w};
#pragma unroll
            for (int a = 0; a < 4; ++a)
#pragma unroll
                for (int b = 0; b < 4; ++b) {
                    accZ[a][b] = fmaf(wa[a], zb[b], accZ[a][b]);
                    accR[a][b] = fmaf(wa[a], rb[b], accR[a][b]);
                }
        }
        float zv[4][4], rv[4][4];
#pragma unroll
        for (int a = 0; a < 4; ++a)
#pragma unroll
            for (int b = 0; b < 4; ++b) {
                zv[a][b] = sigmoidf_(accZ[a][b] + cz_s[j0 + b]);
                rv[a][b] = sigmoidf_(accR[a][b] + cr_s[j0 + b]);
            }
        __syncthreads();
#pragma unroll
        for (int a = 0; a < 4; ++a)
#pragma unroll
            for (int b = 0; b < 4; ++b) {
                const int o = ((j0 + b) << 6) + (i0 + a);
                B0[o] = rv[a][b] * wT[o];
            }
        for (int idx = tid; idx < 4096; idx += 256) {
            const int k = idx >> 6, j = idx & 63;
            B1[idx] = Wh[(64 + k) * 64 + j];
        }
        __syncthreads();
        float accH[4][4] = {{0.f}};
        for (int k = 0; k < 64; ++k) {
            const float4 hv = *(const float4*)&B0[(k << 6) + i0];
            const float4 hj = *(const float4*)&B1[(k << 6) + j0];
            const float ha[4] = {hv.x, hv.y, hv.z, hv.w};
            const float hb[4] = {hj.x, hj.y, hj.z, hj.w};
#pragma unroll
            for (int a = 0; a < 4; ++a)
#pragma unroll
                for (int b = 0; b < 4; ++b)
                    accH[a][b] = fmaf(ha[a], hb[b], accH[a][b]);
        }
        float vpart[4] = {0.f, 0.f, 0.f, 0.f};
#pragma unroll
        for (int a = 0; a < 4; ++a)
#pragma unroll
            for (int b = 0; b < 4; ++b) {
                const int o = ((j0 + b) << 6) + (i0 + a);
                const float h = tanhf(accH[a][b] + ch_s[j0 + b]);
                const float z = zv[a][b];
                const float wn = z * wT[o] + (1.f - z) * h;
                wT[o] = wn;
                vpart[a] = fmaf(wn, wo_s[j0 + b], vpart[a]);
            }
#pragma unroll
        for (int a = 0; a < 4; ++a) {
            float vp = vpart[a];
            vp += __shfl_xor(vp, 1);
            vp += __shfl_xor(vp, 2);
            vp += __shfl_xor(vp, 4);
            vp += __shfl_xor(vp, 8);
            if ((tid & 15) == 0) v_out[t * 64 + i0 + a] = vp;
        }
        __syncthreads();
    }
    for (int idx = tid; idx < 4096; idx += 256) {
        const int i = idx >> 6, j = idx & 63;
        w_final[idx] = wT[(j << 6) | i];
    }
}

__global__ __launch_bounds__(256) void smatvec_kernel(const float* __restrict__ x,
                                                      const float* __restrict__ v,
                                                      float* __restrict__ s) {
    const int t = blockIdx.y;
    const int tid = threadIdx.x;
    const int l4 = tid & 3;
    const int rloc = tid >> 2;
    __shared__ float vs[64];
    if (tid < 64) vs[tid] = v[t * 64 + tid];
    __syncthreads();
    const int row = blockIdx.x * 64 + rloc;
    if (row < N_NODES) {
        const float4* xr = (const float4*)(x + ((size_t)t * N_NODES + row) * D);
        float acc = 0.f;
#pragma unroll
        for (int i = 0; i < 4; ++i) {
            const int c = i * 4 + l4;
            const float4 xv = xr[c];
            acc += xv.x * vs[c * 4 + 0] + xv.y * vs[c * 4 + 1] +
                   xv.z * vs[c * 4 + 2] + xv.w * vs[c * 4 + 3];
        }
        acc += __shfl_xor(acc, 1);
        acc += __shfl_xor(acc, 2);
        if (l4 == 0) s[(size_t)t * N_NODES + row] = acc;
    }
}

// ---------- fast path: hist -> scan -> scatter -> accumulate ----------

// Per-block LDS histogram of dst buckets; 64 edges/thread.
__global__ __launch_bounds__(256) void hist_kernel(const int* __restrict__ dst,
                                                   unsigned* __restrict__ hist) {
    const int t = blockIdx.y;
    const int tid = threadIdx.x;
    __shared__ unsigned h[256];
    h[tid] = 0;
    __syncthreads();
    const int4* dp = (const int4*)(dst + (size_t)t * N_EDGES);
    const int base = blockIdx.x * 4096 + tid;
#pragma unroll
    for (int it = 0; it < 16; ++it) {
        const int i4 = base + it * 256;
        if (i4 < N_E4) {
            const int4 d = dp[i4];
            atomicAdd(&h[d.x >> BKT_BITS], 1u);
            atomicAdd(&h[d.y >> BKT_BITS], 1u);
            atomicAdd(&h[d.z >> BKT_BITS], 1u);
            atomicAdd(&h[d.w >> BKT_BITS], 1u);
        }
    }
    __syncthreads();
    if (h[tid]) atomicAdd(&hist[t * 256 + tid], h[tid]);
}

// Single-block exclusive scan per step -> bucketStart / cursor.
__global__ __launch_bounds__(256) void scan_kernel(const unsigned* __restrict__ hist,
                                                   unsigned* __restrict__ start,
                                                   unsigned* __restrict__ cursor) {
    __shared__ unsigned sc[256];
    const int tid = threadIdx.x;
    for (int t = 0; t < T_STEPS; ++t) {
        const unsigned c = hist[t * 256 + tid];
        unsigned v = c;
        sc[tid] = v;
        __syncthreads();
        for (int off = 1; off < 256; off <<= 1) {
            const unsigned add = (tid >= off) ? sc[tid - off] : 0u;
            __syncthreads();
            v += add;
            sc[tid] = v;
            __syncthreads();
        }
        const unsigned st = (unsigned)(t * N_EDGES) + (v - c);
        start[t * 256 + tid] = st;
        cursor[t * 256 + tid] = st;
        __syncthreads();
    }
}

// Scatter quantized records into bucket regions. 16 edges/thread.
__global__ __launch_bounds__(256) void scatter_kernel(const int* __restrict__ src,
                                                      const int* __restrict__ dst,
                                                      const float* __restrict__ s,
                                                      unsigned* __restrict__ cursor,
                                                      unsigned* __restrict__ recs) {
    const int t = blockIdx.y;
    const int tid = threadIdx.x;
    __shared__ unsigned loff[256];
    loff[tid] = 0;
    __syncthreads();
    const int4* sp = (const int4*)(src + (size_t)t * N_EDGES);
    const int4* dp = (const int4*)(dst + (size_t)t * N_EDGES);
    const float* st = s + (size_t)t * N_NODES;
    unsigned rec[16];
    unsigned bkt[16];
#pragma unroll
    for (int k = 0; k < 16; ++k) bkt[k] = 0xFFFFFFFFu;
    const int base = blockIdx.x * 1024 + tid;
#pragma unroll
    for (int it = 0; it < 4; ++it) {
        const int i4 = base + it * 256;
        if (i4 < N_E4) {
            const int4 sv = sp[i4];
            const int4 dv = dp[i4];
            const int ss[4] = {sv.x, sv.y, sv.z, sv.w};
            const int dd[4] = {dv.x, dv.y, dv.z, dv.w};
#pragma unroll
            for (int j = 0; j < 4; ++j) {
                const int q = (int)llrintf(st[ss[j]] * QSCALE);
                const unsigned b = (unsigned)dd[j] >> BKT_BITS;
                rec[it * 4 + j] = ((unsigned)(dd[j] & (BKT_SIZE - 1)) << 22) |
                                  ((unsigned)q & 0x3FFFFFu);
                bkt[it * 4 + j] = b;
                atomicAdd(&loff[b], 1u);
            }
        }
    }
    __syncthreads();
    const unsigned c = loff[tid];
    __syncthreads();
    const unsigned g = c ? atomicAdd(&cursor[t * 256 + tid], c) : 0u;
    loff[tid] = g;
    __syncthreads();
#pragma unroll
    for (int k = 0; k < 16; ++k) {
        if (bkt[k] != 0xFFFFFFFFu) {
            const unsigned pos = atomicAdd(&loff[bkt[k]], 1u);
            recs[pos] = rec[k];
        }
    }
}

// Per-bucket LDS u64 accumulate + finalize output.
__global__ __launch_bounds__(256) void accum_kernel(const unsigned* __restrict__ recs,
                                                    const unsigned* __restrict__ start,
                                                    const float* __restrict__ bo,
                                                    float* __restrict__ out) {
    const int b = blockIdx.x;
    const int t = blockIdx.y;
    const int tid = threadIdx.x;
    __shared__ unsigned long long bins[BKT_SIZE];
    bins[tid] = 0ULL;
    bins[tid + 256] = 0ULL;
    __syncthreads();
    const unsigned s0 = start[t * 256 + b];
    const unsigned s1 = start[t * 256 + b + 1];
    for (unsigned i = s0 + tid; i < s1; i += 256) {
        const unsigned rec = recs[i];
        const unsigned dl = rec >> 22;
        const long long q = (long long)(((int)(rec << 10)) >> 10);
        atomicAdd(&bins[dl], (unsigned long long)((1ULL << 41) + (unsigned long long)q));
    }
    __syncthreads();
    const float bo0 = bo[0];
#pragma unroll
    for (int k = 0; k < 2; ++k) {
        const int i = tid + k * 256;
        const int node = b * BKT_SIZE + i;
        if (node < N_NODES) {
            const unsigned long long tot = bins[i];
            const unsigned long long deg = (tot + (1ULL << 40)) >> 41;
            const long long rem = (long long)(tot - (deg << 41));
            const float acc = (float)rem * QINV;
            out[(size_t)t * N_NODES + node] = bo0 + acc / fmaxf((float)deg, 1.f);
        }
    }
}

// ---------- fallback path (round-2 proven): packed global atomics ----------

__global__ __launch_bounds__(256) void edge_kernel(const int* __restrict__ src,
                                                   const int* __restrict__ dst,
                                                   const float* __restrict__ s,
                                                   unsigned long long* __restrict__ packed) {
    const int t = blockIdx.y;
    const int e4 = blockIdx.x * 256 + threadIdx.x;
    if (e4 * 4 >= N_EDGES) return;
    const int4* sp = (const int4*)(src + (size_t)t * N_EDGES);
    const int4* dp = (const int4*)(dst + (size_t)t * N_EDGES);
    const float* st = s + (size_t)t * N_NODES;
    unsigned long long* pk = packed + (size_t)t * N_NODES;
    const int4 s4 = sp[e4];
    const int4 d4 = dp[e4];
    const float v0 = st[s4.x], v1 = st[s4.y], v2 = st[s4.z], v3 = st[s4.w];
    const unsigned long long base = 1ULL << 41;
    atomicAdd(&pk[d4.x], base + (unsigned long long)(long long)llrintf(v0 * PACK_SCALE));
    atomicAdd(&pk[d4.y], base + (unsigned long long)(long long)llrintf(v1 * PACK_SCALE));
    atomicAdd(&pk[d4.z], base + (unsigned long long)(long long)llrintf(v2 * PACK_SCALE));
    atomicAdd(&pk[d4.w], base + (unsigned long long)(long long)llrintf(v3 * PACK_SCALE));
}

__global__ __launch_bounds__(256) void out_kernel(const unsigned long long* __restrict__ packed,
                                                  const float* __restrict__ bo,
                                                  float* __restrict__ out) {
    const int i = blockIdx.x * 256 + threadIdx.x;
    if (i < T_STEPS * N_NODES) {
        const unsigned long long tot = packed[i];
        const unsigned long long deg = (tot + (1ULL << 40)) >> 41;
        const long long rem = (long long)(tot - (deg << 41));
        const float acc = (float)rem * PACK_INV;
        out[i] = bo[0] + acc / fmaxf((float)deg, 1.0f);
    }
}

extern "C" void kernel_launch(void* const* d_in, const int* in_sizes, int n_in,
                              void* d_out, int out_size, void* d_ws, size_t ws_size,
                              hipStream_t stream) {
    const float* x  = (const float*)d_in[0];
    const int* src  = (const int*)d_in[1];
    const int* dst  = (const int*)d_in[2];
    const float* iw = (const float*)d_in[3];
    const float* Wz = (const float*)d_in[4];
    const float* bz = (const float*)d_in[5];
    const float* Wr = (const float*)d_in[6];
    const float* br = (const float*)d_in[7];
    const float* Wh = (const float*)d_in[8];
    const float* bh = (const float*)d_in[9];
    const float* Wp = (const float*)d_in[10];
    const float* bp = (const float*)d_in[11];
    const float* Wo = (const float*)d_in[12];
    const float* bo = (const float*)d_in[13];
    float* out = (float*)d_out;   // [3*N outs][64*64 w_final]
    float* ws  = (float*)d_ws;

    const size_t FAST_NEED = (size_t)5102688 * sizeof(float);
    if (ws_size >= FAST_NEED) {
        float* colsum = ws;                                   // 192 f
        float* vbuf   = ws + 192;                             // 192 f
        float* sbuf   = ws + 384;                             // 300000 f
        unsigned* hist   = (unsigned*)(ws + 300384);          // 768 u32
        unsigned* bstart = (unsigned*)(ws + 301152);          // 768 u32
        unsigned* cursor = (unsigned*)(ws + 301920);          // 768 u32
        unsigned* recs   = (unsigned*)(ws + 302688);          // 4.8M u32

        hipMemsetAsync(colsum, 0, 192 * sizeof(float), stream);
        hipMemsetAsync(hist, 0, 768 * sizeof(unsigned), stream);

        hist_kernel<<<dim3(98, 3), 256, 0, stream>>>(dst, hist);
        scan_kernel<<<1, 256, 0, stream>>>(hist, bstart, cursor);
        colsum_kernel<<<dim3(782, 3), 256, 0, stream>>>(x, colsum);
        gru_kernel<<<1, 256, 0, stream>>>(colsum, iw, Wz, bz, Wr, br, Wh, bh,
                                          Wp, bp, Wo, vbuf,
                                          out + (size_t)T_STEPS * N_NODES);
        smatvec_kernel<<<dim3(1563, 3), 256, 0, stream>>>(x, vbuf, sbuf);
        scatter_kernel<<<dim3(391, 3), 256, 0, stream>>>(src, dst, sbuf, cursor, recs);
        accum_kernel<<<dim3(NBKT, 3), 256, 0, stream>>>(recs, bstart, bo, out);
    } else {
        float* colsum = ws;
        unsigned long long* packed = (unsigned long long*)(ws + 192);
        float* vbuf   = ws + 600192;
        float* sbuf   = ws + 600384;

        hipMemsetAsync(ws, 0, (size_t)600192 * sizeof(float), stream);

        colsum_kernel<<<dim3(782, 3), 256, 0, stream>>>(x, colsum);
        gru_kernel<<<1, 256, 0, stream>>>(colsum, iw, Wz, bz, Wr, br, Wh, bh,
                                          Wp, bp, Wo, vbuf,
                                          out + (size_t)T_STEPS * N_NODES);
        smatvec_kernel<<<dim3(1563, 3), 256, 0, stream>>>(x, vbuf, sbuf);
        edge_kernel<<<dim3(1563, 3), 256, 0, stream>>>(src, dst, sbuf, packed);
        out_kernel<<<1172, 256, 0, stream>>>(packed, bo, out);
    }
}

// Round 4
// 155.967 us; speedup vs baseline: 4.4251x; 1.8008x over previous
//
#include <hip/hip_runtime.h>
#include <math.h>

#define T_STEPS 3
#define N_NODES 100000
#define N_EDGES 1600000
#define N_E4    (N_EDGES / 4)
#define D 64

// Bucketed-scatter parameters
#define BKT_BITS 9
#define BKT_SIZE 512
#define NBKT 196            // ceil(100000/512)
#define QSCALE 65536.0f     // 2^16
#define QINV   (1.0f / 65536.0f)

// Fallback (packed global atomic) parameters
#define PACK_SCALE 1048576.0f
#define PACK_INV   (1.0f / 1048576.0f)

// ---------------------------------------------------------------------------
// FAST ws layout (float offsets):
//   [0,192)            colsum[3][64]     (memset)
//   [192,384)          v[3][64]
//   [384,300384)       s[3][N]
//   [300384,301152)    hist[3][256] u32  (memset)
//   [301152,301920)    bucketStart[3][256] u32 (written by scan)
//   [301920,302688)    cursor[3][256] u32      (written by scan)
//   [302688,5102688)   recs[3][E] u32
// FALLBACK layout = round-2 layout.
// ---------------------------------------------------------------------------

__global__ __launch_bounds__(256) void colsum_kernel(const float* __restrict__ x,
                                                     float* __restrict__ colsum) {
    const int t = blockIdx.y;
    const int tid = threadIdx.x;
    const int q = tid & 15;
    const int g = tid >> 4;
    const float4* xt = (const float4*)(x + (size_t)t * N_NODES * D);
    const int base = blockIdx.x * 128;
    float sx = 0.f, sy = 0.f, sz = 0.f, sw = 0.f;
#pragma unroll
    for (int it = 0; it < 8; ++it) {
        const int r = base + g + 16 * it;
        if (r < N_NODES) {
            const float4 vv = xt[(size_t)r * 16 + q];
            sx += vv.x; sy += vv.y; sz += vv.z; sw += vv.w;
        }
    }
    __shared__ float red[16][64];
    red[g][q * 4 + 0] = sx;
    red[g][q * 4 + 1] = sy;
    red[g][q * 4 + 2] = sz;
    red[g][q * 4 + 3] = sw;
    __syncthreads();
    if (tid < 64) {
        float s = 0.f;
#pragma unroll
        for (int gg = 0; gg < 16; ++gg) s += red[gg][tid];
        atomicAdd(&colsum[t * 64 + tid], s);
    }
}

__device__ __forceinline__ float fast_sigmoid(float v) {
    return 1.f / (1.f + __expf(-v));
}
__device__ __forceinline__ float fast_tanh(float v) {
    return 1.f - 2.f / (__expf(2.f * v) + 1.f);
}

// 1024-thread GRU: 16 waves on one CU (4/SIMD) for latency hiding.
// Thread owns a 2x2 tile of the 64x64 weight, kept in registers across steps.
// LDS: wR (w row-major), rwR (r*w row-major), WzB/WrB/WhB (bottom halves),
// part (matvec partials), sml (mean|ctx|czr|wo).
__global__ __launch_bounds__(1024) void gru1024_kernel(
    const float* __restrict__ colsum, const float* __restrict__ iw,
    const float* __restrict__ Wz, const float* __restrict__ bz,
    const float* __restrict__ Wr, const float* __restrict__ br,
    const float* __restrict__ Wh, const float* __restrict__ bh,
    const float* __restrict__ Wp, const float* __restrict__ bp,
    const float* __restrict__ Wo,
    float* __restrict__ v_out, float* __restrict__ w_final) {
    __shared__ float wR[4096];    // w[i][k] row-major
    __shared__ float rwR[4096];   // (r*w)[i][k] row-major
    __shared__ float WzB[4096];   // Wz rows 64..127, [k][j]
    __shared__ float WrB[4096];
    __shared__ float WhB[4096];
    __shared__ float part[3072];
    __shared__ float sml[384];    // mean|ctx|czr[3][64]|wo
    float* mean_s = sml;
    float* ctx_s  = sml + 64;
    float* czr_s  = sml + 128;
    float* wo_s   = sml + 320;

    const int tid = threadIdx.x;
    ((float4*)wR)[tid]  = ((const float4*)iw)[tid];
    ((float4*)WzB)[tid] = ((const float4*)(Wz + 4096))[tid];
    ((float4*)WrB)[tid] = ((const float4*)(Wr + 4096))[tid];
    ((float4*)WhB)[tid] = ((const float4*)(Wh + 4096))[tid];
    if (tid < 64) wo_s[tid] = Wo[tid];
    __syncthreads();

    const int j2 = (tid & 31) * 2;   // col pair
    const int i2 = (tid >> 5) * 2;   // row pair
    const int jm = tid & 63;         // matvec col
    const int g  = tid >> 6;         // matvec k-group (= wave id)

    float w00 = wR[i2 * 64 + j2],       w01 = wR[i2 * 64 + j2 + 1];
    float w10 = wR[(i2 + 1) * 64 + j2], w11 = wR[(i2 + 1) * 64 + j2 + 1];

    for (int t = 0; t < T_STEPS; ++t) {
        if (tid < 64) mean_s[tid] = colsum[t * 64 + tid] * (1.f / (float)N_NODES);
        __syncthreads();
        // ctx = mean @ Wp + bp (16-way parallel partials)
        {
            float p = 0.f;
#pragma unroll
            for (int kk = 0; kk < 4; ++kk)
                p = fmaf(mean_s[4 * g + kk], Wp[(4 * g + kk) * 64 + jm], p);
            part[g * 64 + jm] = p;
        }
        __syncthreads();
        if (tid < 64) {
            float c = bp[tid];
#pragma unroll
            for (int gg = 0; gg < 16; ++gg) c += part[gg * 64 + tid];
            ctx_s[tid] = c;
        }
        __syncthreads();
        // cz/cr/ch = ctx @ {Wz,Wr,Wh}_top + {bz,br,bh}
        {
            float p0 = 0.f, p1 = 0.f, p2 = 0.f;
#pragma unroll
            for (int kk = 0; kk < 4; ++kk) {
                const float c = ctx_s[4 * g + kk];
                const int o = (4 * g + kk) * 64 + jm;
                p0 = fmaf(c, Wz[o], p0);
                p1 = fmaf(c, Wr[o], p1);
                p2 = fmaf(c, Wh[o], p2);
            }
            part[g * 64 + jm] = p0;
            part[1024 + g * 64 + jm] = p1;
            part[2048 + g * 64 + jm] = p2;
        }
        __syncthreads();
        if (tid < 192) {
            const int m = tid >> 6, j = tid & 63;
            float c = (m == 0 ? bz[j] : (m == 1 ? br[j] : bh[j]));
#pragma unroll
            for (int gg = 0; gg < 16; ++gg) c += part[m * 1024 + gg * 64 + j];
            czr_s[m * 64 + j] = c;
        }
        __syncthreads();
        // z/r matmuls: acc = w @ {WzB,WrB}
        float z00 = 0, z01 = 0, z10 = 0, z11 = 0;
        float r00 = 0, r01 = 0, r10 = 0, r11 = 0;
        for (int k0 = 0; k0 < 64; k0 += 4) {
            const float4 a0 = *(const float4*)&wR[i2 * 64 + k0];
            const float4 a1 = *(const float4*)&wR[(i2 + 1) * 64 + k0];
            const float a0v[4] = {a0.x, a0.y, a0.z, a0.w};
            const float a1v[4] = {a1.x, a1.y, a1.z, a1.w};
#pragma unroll
            for (int kk = 0; kk < 4; ++kk) {
                const float2 bzv = *(const float2*)&WzB[(k0 + kk) * 64 + j2];
                const float2 brv = *(const float2*)&WrB[(k0 + kk) * 64 + j2];
                z00 = fmaf(a0v[kk], bzv.x, z00); z01 = fmaf(a0v[kk], bzv.y, z01);
                z10 = fmaf(a1v[kk], bzv.x, z10); z11 = fmaf(a1v[kk], bzv.y, z11);
                r00 = fmaf(a0v[kk], brv.x, r00); r01 = fmaf(a0v[kk], brv.y, r01);
                r10 = fmaf(a1v[kk], brv.x, r10); r11 = fmaf(a1v[kk], brv.y, r11);
            }
        }
        {
            const float cz0 = czr_s[j2], cz1 = czr_s[j2 + 1];
            const float cr0 = czr_s[64 + j2], cr1 = czr_s[64 + j2 + 1];
            z00 = fast_sigmoid(z00 + cz0); z01 = fast_sigmoid(z01 + cz1);
            z10 = fast_sigmoid(z10 + cz0); z11 = fast_sigmoid(z11 + cz1);
            r00 = fast_sigmoid(r00 + cr0); r01 = fast_sigmoid(r01 + cr1);
            r10 = fast_sigmoid(r10 + cr0); r11 = fast_sigmoid(r11 + cr1);
        }
        // rw = r * w_old (row-major, conflict-free writes)
        rwR[i2 * 64 + j2] = r00 * w00;       rwR[i2 * 64 + j2 + 1] = r01 * w01;
        rwR[(i2 + 1) * 64 + j2] = r10 * w10; rwR[(i2 + 1) * 64 + j2 + 1] = r11 * w11;
        __syncthreads();
        // h_tilde matmul: (r*w) @ WhB
        float h00 = 0, h01 = 0, h10 = 0, h11 = 0;
        for (int k0 = 0; k0 < 64; k0 += 4) {
            const float4 a0 = *(const float4*)&rwR[i2 * 64 + k0];
            const float4 a1 = *(const float4*)&rwR[(i2 + 1) * 64 + k0];
            const float a0v[4] = {a0.x, a0.y, a0.z, a0.w};
            const float a1v[4] = {a1.x, a1.y, a1.z, a1.w};
#pragma unroll
            for (int kk = 0; kk < 4; ++kk) {
                const float2 bhv = *(const float2*)&WhB[(k0 + kk) * 64 + j2];
                h00 = fmaf(a0v[kk], bhv.x, h00); h01 = fmaf(a0v[kk], bhv.y, h01);
                h10 = fmaf(a1v[kk], bhv.x, h10); h11 = fmaf(a1v[kk], bhv.y, h11);
            }
        }
        {
            const float ch0 = czr_s[128 + j2], ch1 = czr_s[128 + j2 + 1];
            h00 = fast_tanh(h00 + ch0); h01 = fast_tanh(h01 + ch1);
            h10 = fast_tanh(h10 + ch0); h11 = fast_tanh(h11 + ch1);
        }
        // w_new = z*w + (1-z)*h  (registers)
        w00 = z00 * w00 + (1.f - z00) * h00;
        w01 = z01 * w01 + (1.f - z01) * h01;
        w10 = z10 * w10 + (1.f - z10) * h10;
        w11 = z11 * w11 + (1.f - z11) * h11;
        // v_t = w_new @ Wo : per-half-wave xor reduce over j
        {
            const float wo0 = wo_s[j2], wo1 = wo_s[j2 + 1];
            float vp0 = w00 * wo0 + w01 * wo1;
            float vp1 = w10 * wo0 + w11 * wo1;
            vp0 += __shfl_xor(vp0, 1);  vp1 += __shfl_xor(vp1, 1);
            vp0 += __shfl_xor(vp0, 2);  vp1 += __shfl_xor(vp1, 2);
            vp0 += __shfl_xor(vp0, 4);  vp1 += __shfl_xor(vp1, 4);
            vp0 += __shfl_xor(vp0, 8);  vp1 += __shfl_xor(vp1, 8);
            vp0 += __shfl_xor(vp0, 16); vp1 += __shfl_xor(vp1, 16);
            if ((tid & 31) == 0) {
                v_out[t * 64 + i2]     = vp0;
                v_out[t * 64 + i2 + 1] = vp1;
            }
        }
        // publish w_new for next step's matmuls
        wR[i2 * 64 + j2] = w00;       wR[i2 * 64 + j2 + 1] = w01;
        wR[(i2 + 1) * 64 + j2] = w10; wR[(i2 + 1) * 64 + j2 + 1] = w11;
        __syncthreads();
    }
    w_final[i2 * 64 + j2] = w00;       w_final[i2 * 64 + j2 + 1] = w01;
    w_final[(i2 + 1) * 64 + j2] = w10; w_final[(i2 + 1) * 64 + j2 + 1] = w11;
}

__global__ __launch_bounds__(256) void smatvec_kernel(const float* __restrict__ x,
                                                      const float* __restrict__ v,
                                                      float* __restrict__ s) {
    const int t = blockIdx.y;
    const int tid = threadIdx.x;
    const int l4 = tid & 3;
    const int rloc = tid >> 2;
    __shared__ float vs[64];
    if (tid < 64) vs[tid] = v[t * 64 + tid];
    __syncthreads();
    const int row = blockIdx.x * 64 + rloc;
    if (row < N_NODES) {
        const float4* xr = (const float4*)(x + ((size_t)t * N_NODES + row) * D);
        float acc = 0.f;
#pragma unroll
        for (int i = 0; i < 4; ++i) {
            const int c = i * 4 + l4;
            const float4 xv = xr[c];
            acc += xv.x * vs[c * 4 + 0] + xv.y * vs[c * 4 + 1] +
                   xv.z * vs[c * 4 + 2] + xv.w * vs[c * 4 + 3];
        }
        acc += __shfl_xor(acc, 1);
        acc += __shfl_xor(acc, 2);
        if (l4 == 0) s[(size_t)t * N_NODES + row] = acc;
    }
}

// ---------- fast path: hist -> scan -> scatter -> accumulate ----------

__global__ __launch_bounds__(256) void hist_kernel(const int* __restrict__ dst,
                                                   unsigned* __restrict__ hist) {
    const int t = blockIdx.y;
    const int tid = threadIdx.x;
    __shared__ unsigned h[256];
    h[tid] = 0;
    __syncthreads();
    const int4* dp = (const int4*)(dst + (size_t)t * N_EDGES);
    const int base = blockIdx.x * 4096 + tid;
#pragma unroll
    for (int it = 0; it < 16; ++it) {
        const int i4 = base + it * 256;
        if (i4 < N_E4) {
            const int4 d = dp[i4];
            atomicAdd(&h[d.x >> BKT_BITS], 1u);
            atomicAdd(&h[d.y >> BKT_BITS], 1u);
            atomicAdd(&h[d.z >> BKT_BITS], 1u);
            atomicAdd(&h[d.w >> BKT_BITS], 1u);
        }
    }
    __syncthreads();
    if (h[tid]) atomicAdd(&hist[t * 256 + tid], h[tid]);
}

__global__ __launch_bounds__(256) void scan_kernel(const unsigned* __restrict__ hist,
                                                   unsigned* __restrict__ start,
                                                   unsigned* __restrict__ cursor) {
    __shared__ unsigned sc[256];
    const int tid = threadIdx.x;
    for (int t = 0; t < T_STEPS; ++t) {
        const unsigned c = hist[t * 256 + tid];
        unsigned v = c;
        sc[tid] = v;
        __syncthreads();
        for (int off = 1; off < 256; off <<= 1) {
            const unsigned add = (tid >= off) ? sc[tid - off] : 0u;
            __syncthreads();
            v += add;
            sc[tid] = v;
            __syncthreads();
        }
        const unsigned st = (unsigned)(t * N_EDGES) + (v - c);
        start[t * 256 + tid] = st;
        cursor[t * 256 + tid] = st;
        __syncthreads();
    }
}

__global__ __launch_bounds__(256) void scatter_kernel(const int* __restrict__ src,
                                                      const int* __restrict__ dst,
                                                      const float* __restrict__ s,
                                                      unsigned* __restrict__ cursor,
                                                      unsigned* __restrict__ recs) {
    const int t = blockIdx.y;
    const int tid = threadIdx.x;
    __shared__ unsigned loff[256];
    loff[tid] = 0;
    __syncthreads();
    const int4* sp = (const int4*)(src + (size_t)t * N_EDGES);
    const int4* dp = (const int4*)(dst + (size_t)t * N_EDGES);
    const float* st = s + (size_t)t * N_NODES;
    unsigned rec[16];
    unsigned bkt[16];
#pragma unroll
    for (int k = 0; k < 16; ++k) bkt[k] = 0xFFFFFFFFu;
    const int base = blockIdx.x * 1024 + tid;
#pragma unroll
    for (int it = 0; it < 4; ++it) {
        const int i4 = base + it * 256;
        if (i4 < N_E4) {
            const int4 sv = sp[i4];
            const int4 dv = dp[i4];
            const int ss[4] = {sv.x, sv.y, sv.z, sv.w};
            const int dd[4] = {dv.x, dv.y, dv.z, dv.w};
#pragma unroll
            for (int j = 0; j < 4; ++j) {
                const int q = (int)llrintf(st[ss[j]] * QSCALE);
                const unsigned b = (unsigned)dd[j] >> BKT_BITS;
                rec[it * 4 + j] = ((unsigned)(dd[j] & (BKT_SIZE - 1)) << 22) |
                                  ((unsigned)q & 0x3FFFFFu);
                bkt[it * 4 + j] = b;
                atomicAdd(&loff[b], 1u);
            }
        }
    }
    __syncthreads();
    const unsigned c = loff[tid];
    __syncthreads();
    const unsigned g = c ? atomicAdd(&cursor[t * 256 + tid], c) : 0u;
    loff[tid] = g;
    __syncthreads();
#pragma unroll
    for (int k = 0; k < 16; ++k) {
        if (bkt[k] != 0xFFFFFFFFu) {
            const unsigned pos = atomicAdd(&loff[bkt[k]], 1u);
            recs[pos] = rec[k];
        }
    }
}

__global__ __launch_bounds__(256) void accum_kernel(const unsigned* __restrict__ recs,
                                                    const unsigned* __restrict__ start,
                                                    const float* __restrict__ bo,
                                                    float* __restrict__ out) {
    const int b = blockIdx.x;
    const int t = blockIdx.y;
    const int tid = threadIdx.x;
    __shared__ unsigned long long bins[BKT_SIZE];
    bins[tid] = 0ULL;
    bins[tid + 256] = 0ULL;
    __syncthreads();
    const unsigned s0 = start[t * 256 + b];
    const unsigned s1 = start[t * 256 + b + 1];
    for (unsigned i = s0 + tid; i < s1; i += 256) {
        const unsigned rec = recs[i];
        const unsigned dl = rec >> 22;
        const long long q = (long long)(((int)(rec << 10)) >> 10);
        atomicAdd(&bins[dl], (unsigned long long)((1ULL << 41) + (unsigned long long)q));
    }
    __syncthreads();
    const float bo0 = bo[0];
#pragma unroll
    for (int k = 0; k < 2; ++k) {
        const int i = tid + k * 256;
        const int node = b * BKT_SIZE + i;
        if (node < N_NODES) {
            const unsigned long long tot = bins[i];
            const unsigned long long deg = (tot + (1ULL << 40)) >> 41;
            const long long rem = (long long)(tot - (deg << 41));
            const float acc = (float)rem * QINV;
            out[(size_t)t * N_NODES + node] = bo0 + acc / fmaxf((float)deg, 1.f);
        }
    }
}

// ---------- fallback path (round-2 proven): packed global atomics ----------

__global__ __launch_bounds__(256) void edge_kernel(const int* __restrict__ src,
                                                   const int* __restrict__ dst,
                                                   const float* __restrict__ s,
                                                   unsigned long long* __restrict__ packed) {
    const int t = blockIdx.y;
    const int e4 = blockIdx.x * 256 + threadIdx.x;
    if (e4 * 4 >= N_EDGES) return;
    const int4* sp = (const int4*)(src + (size_t)t * N_EDGES);
    const int4* dp = (const int4*)(dst + (size_t)t * N_EDGES);
    const float* st = s + (size_t)t * N_NODES;
    unsigned long long* pk = packed + (size_t)t * N_NODES;
    const int4 s4 = sp[e4];
    const int4 d4 = dp[e4];
    const float v0 = st[s4.x], v1 = st[s4.y], v2 = st[s4.z], v3 = st[s4.w];
    const unsigned long long base = 1ULL << 41;
    atomicAdd(&pk[d4.x], base + (unsigned long long)(long long)llrintf(v0 * PACK_SCALE));
    atomicAdd(&pk[d4.y], base + (unsigned long long)(long long)llrintf(v1 * PACK_SCALE));
    atomicAdd(&pk[d4.z], base + (unsigned long long)(long long)llrintf(v2 * PACK_SCALE));
    atomicAdd(&pk[d4.w], base + (unsigned long long)(long long)llrintf(v3 * PACK_SCALE));
}

__global__ __launch_bounds__(256) void out_kernel(const unsigned long long* __restrict__ packed,
                                                  const float* __restrict__ bo,
                                                  float* __restrict__ out) {
    const int i = blockIdx.x * 256 + threadIdx.x;
    if (i < T_STEPS * N_NODES) {
        const unsigned long long tot = packed[i];
        const unsigned long long deg = (tot + (1ULL << 40)) >> 41;
        const long long rem = (long long)(tot - (deg << 41));
        const float acc = (float)rem * PACK_INV;
        out[i] = bo[0] + acc / fmaxf(deg, 1.0f);
    }
}

extern "C" void kernel_launch(void* const* d_in, const int* in_sizes, int n_in,
                              void* d_out, int out_size, void* d_ws, size_t ws_size,
                              hipStream_t stream) {
    const float* x  = (const float*)d_in[0];
    const int* src  = (const int*)d_in[1];
    const int* dst  = (const int*)d_in[2];
    const float* iw = (const float*)d_in[3];
    const float* Wz = (const float*)d_in[4];
    const float* bz = (const float*)d_in[5];
    const float* Wr = (const float*)d_in[6];
    const float* br = (const float*)d_in[7];
    const float* Wh = (const float*)d_in[8];
    const float* bh = (const float*)d_in[9];
    const float* Wp = (const float*)d_in[10];
    const float* bp = (const float*)d_in[11];
    const float* Wo = (const float*)d_in[12];
    const float* bo = (const float*)d_in[13];
    float* out = (float*)d_out;   // [3*N outs][64*64 w_final]
    float* ws  = (float*)d_ws;

    const size_t FAST_NEED = (size_t)5102688 * sizeof(float);
    if (ws_size >= FAST_NEED) {
        float* colsum = ws;                                   // 192 f
        float* vbuf   = ws + 192;                             // 192 f
        float* sbuf   = ws + 384;                             // 300000 f
        unsigned* hist   = (unsigned*)(ws + 300384);          // 768 u32
        unsigned* bstart = (unsigned*)(ws + 301152);          // 768 u32
        unsigned* cursor = (unsigned*)(ws + 301920);          // 768 u32
        unsigned* recs   = (unsigned*)(ws + 302688);          // 4.8M u32

        hipMemsetAsync(colsum, 0, 192 * sizeof(float), stream);
        hipMemsetAsync(hist, 0, 768 * sizeof(unsigned), stream);

        colsum_kernel<<<dim3(782, 3), 256, 0, stream>>>(x, colsum);
        gru1024_kernel<<<1, 1024, 0, stream>>>(colsum, iw, Wz, bz, Wr, br, Wh, bh,
                                               Wp, bp, Wo, vbuf,
                                               out + (size_t)T_STEPS * N_NODES);
        hist_kernel<<<dim3(98, 3), 256, 0, stream>>>(dst, hist);
        scan_kernel<<<1, 256, 0, stream>>>(hist, bstart, cursor);
        smatvec_kernel<<<dim3(1563, 3), 256, 0, stream>>>(x, vbuf, sbuf);
        scatter_kernel<<<dim3(391, 3), 256, 0, stream>>>(src, dst, sbuf, cursor, recs);
        accum_kernel<<<dim3(NBKT, 3), 256, 0, stream>>>(recs, bstart, bo, out);
    } else {
        float* colsum = ws;
        unsigned long long* packed = (unsigned long long*)(ws + 192);
        float* vbuf   = ws + 600192;
        float* sbuf   = ws + 600384;

        hipMemsetAsync(ws, 0, (size_t)600192 * sizeof(float), stream);

        colsum_kernel<<<dim3(782, 3), 256, 0, stream>>>(x, colsum);
        gru1024_kernel<<<1, 1024, 0, stream>>>(colsum, iw, Wz, bz, Wr, br, Wh, bh,
                                               Wp, bp, Wo, vbuf,
                                               out + (size_t)T_STEPS * N_NODES);
        smatvec_kernel<<<dim3(1563, 3), 256, 0, stream>>>(x, vbuf, sbuf);
        edge_kernel<<<dim3(1563, 3), 256, 0, stream>>>(src, dst, sbuf, packed);
        out_kernel<<<1172, 256, 0, stream>>>(packed, bo, out);
    }
}

// Round 5
// 145.558 us; speedup vs baseline: 4.7416x; 1.0715x over previous
//
#include <hip/hip_runtime.h>
#include <math.h>

#define T_STEPS 3
#define N_NODES 100000
#define N_EDGES 1600000
#define N_E4    (N_EDGES / 4)
#define D 64

// Bucketed-scatter parameters
#define BKT_BITS 9
#define BKT_SIZE 512
#define NBKT 196            // ceil(100000/512)
#define QSCALE 65536.0f     // 2^16
#define QINV   (1.0f / 65536.0f)

// Sorting-scatter parameters
#define SC_EPB 8192         // edges per scatter block
#define SC_I4  2048         // int4 per scatter block
#define SC_BLOCKS 196       // ceil(1.6M / 8192)

// Fallback (packed global atomic) parameters
#define PACK_SCALE 1048576.0f
#define PACK_INV   (1.0f / 1048576.0f)

// ---------------------------------------------------------------------------
// FAST ws layout (float offsets):
//   [0,192)            colsum[3][64]     (memset)
//   [192,384)          v[3][64]
//   [384,300384)       s[3][N]
//   [300384,301152)    hist[3][256] u32  (memset)
//   [301152,301920)    bucketStart[3][256] u32 (written by scan)
//   [301920,302688)    cursor[3][256] u32      (written by scan)
//   [302688,5102688)   recs[3][E] u32
// FALLBACK layout = round-2 layout.
// ---------------------------------------------------------------------------

__global__ __launch_bounds__(256) void colsum_kernel(const float* __restrict__ x,
                                                     float* __restrict__ colsum) {
    const int t = blockIdx.y;
    const int tid = threadIdx.x;
    const int q = tid & 15;
    const int g = tid >> 4;
    const float4* xt = (const float4*)(x + (size_t)t * N_NODES * D);
    const int base = blockIdx.x * 128;
    float sx = 0.f, sy = 0.f, sz = 0.f, sw = 0.f;
#pragma unroll
    for (int it = 0; it < 8; ++it) {
        const int r = base + g + 16 * it;
        if (r < N_NODES) {
            const float4 vv = xt[(size_t)r * 16 + q];
            sx += vv.x; sy += vv.y; sz += vv.z; sw += vv.w;
        }
    }
    __shared__ float red[16][64];
    red[g][q * 4 + 0] = sx;
    red[g][q * 4 + 1] = sy;
    red[g][q * 4 + 2] = sz;
    red[g][q * 4 + 3] = sw;
    __syncthreads();
    if (tid < 64) {
        float s = 0.f;
#pragma unroll
        for (int gg = 0; gg < 16; ++gg) s += red[gg][tid];
        atomicAdd(&colsum[t * 64 + tid], s);
    }
}

__device__ __forceinline__ float fast_sigmoid(float v) {
    return 1.f / (1.f + __expf(-v));
}
__device__ __forceinline__ float fast_tanh(float v) {
    return 1.f - 2.f / (__expf(2.f * v) + 1.f);
}

// 1024-thread GRU: 16 waves on one CU (4/SIMD) for latency hiding.
__global__ __launch_bounds__(1024) void gru1024_kernel(
    const float* __restrict__ colsum, const float* __restrict__ iw,
    const float* __restrict__ Wz, const float* __restrict__ bz,
    const float* __restrict__ Wr, const float* __restrict__ br,
    const float* __restrict__ Wh, const float* __restrict__ bh,
    const float* __restrict__ Wp, const float* __restrict__ bp,
    const float* __restrict__ Wo,
    float* __restrict__ v_out, float* __restrict__ w_final) {
    __shared__ float wR[4096];    // w[i][k] row-major
    __shared__ float rwR[4096];   // (r*w)[i][k] row-major
    __shared__ float WzB[4096];   // Wz rows 64..127, [k][j]
    __shared__ float WrB[4096];
    __shared__ float WhB[4096];
    __shared__ float part[3072];
    __shared__ float sml[384];    // mean|ctx|czr[3][64]|wo
    float* mean_s = sml;
    float* ctx_s  = sml + 64;
    float* czr_s  = sml + 128;
    float* wo_s   = sml + 320;

    const int tid = threadIdx.x;
    ((float4*)wR)[tid]  = ((const float4*)iw)[tid];
    ((float4*)WzB)[tid] = ((const float4*)(Wz + 4096))[tid];
    ((float4*)WrB)[tid] = ((const float4*)(Wr + 4096))[tid];
    ((float4*)WhB)[tid] = ((const float4*)(Wh + 4096))[tid];
    if (tid < 64) wo_s[tid] = Wo[tid];
    __syncthreads();

    const int j2 = (tid & 31) * 2;   // col pair
    const int i2 = (tid >> 5) * 2;   // row pair
    const int jm = tid & 63;         // matvec col
    const int g  = tid >> 6;         // matvec k-group (= wave id)

    float w00 = wR[i2 * 64 + j2],       w01 = wR[i2 * 64 + j2 + 1];
    float w10 = wR[(i2 + 1) * 64 + j2], w11 = wR[(i2 + 1) * 64 + j2 + 1];

    for (int t = 0; t < T_STEPS; ++t) {
        if (tid < 64) mean_s[tid] = colsum[t * 64 + tid] * (1.f / (float)N_NODES);
        __syncthreads();
        {
            float p = 0.f;
#pragma unroll
            for (int kk = 0; kk < 4; ++kk)
                p = fmaf(mean_s[4 * g + kk], Wp[(4 * g + kk) * 64 + jm], p);
            part[g * 64 + jm] = p;
        }
        __syncthreads();
        if (tid < 64) {
            float c = bp[tid];
#pragma unroll
            for (int gg = 0; gg < 16; ++gg) c += part[gg * 64 + tid];
            ctx_s[tid] = c;
        }
        __syncthreads();
        {
            float p0 = 0.f, p1 = 0.f, p2 = 0.f;
#pragma unroll
            for (int kk = 0; kk < 4; ++kk) {
                const float c = ctx_s[4 * g + kk];
                const int o = (4 * g + kk) * 64 + jm;
                p0 = fmaf(c, Wz[o], p0);
                p1 = fmaf(c, Wr[o], p1);
                p2 = fmaf(c, Wh[o], p2);
            }
            part[g * 64 + jm] = p0;
            part[1024 + g * 64 + jm] = p1;
            part[2048 + g * 64 + jm] = p2;
        }
        __syncthreads();
        if (tid < 192) {
            const int m = tid >> 6, j = tid & 63;
            float c = (m == 0 ? bz[j] : (m == 1 ? br[j] : bh[j]));
#pragma unroll
            for (int gg = 0; gg < 16; ++gg) c += part[m * 1024 + gg * 64 + j];
            czr_s[m * 64 + j] = c;
        }
        __syncthreads();
        float z00 = 0, z01 = 0, z10 = 0, z11 = 0;
        float r00 = 0, r01 = 0, r10 = 0, r11 = 0;
        for (int k0 = 0; k0 < 64; k0 += 4) {
            const float4 a0 = *(const float4*)&wR[i2 * 64 + k0];
            const float4 a1 = *(const float4*)&wR[(i2 + 1) * 64 + k0];
            const float a0v[4] = {a0.x, a0.y, a0.z, a0.w};
            const float a1v[4] = {a1.x, a1.y, a1.z, a1.w};
#pragma unroll
            for (int kk = 0; kk < 4; ++kk) {
                const float2 bzv = *(const float2*)&WzB[(k0 + kk) * 64 + j2];
                const float2 brv = *(const float2*)&WrB[(k0 + kk) * 64 + j2];
                z00 = fmaf(a0v[kk], bzv.x, z00); z01 = fmaf(a0v[kk], bzv.y, z01);
                z10 = fmaf(a1v[kk], bzv.x, z10); z11 = fmaf(a1v[kk], bzv.y, z11);
                r00 = fmaf(a0v[kk], brv.x, r00); r01 = fmaf(a0v[kk], brv.y, r01);
                r10 = fmaf(a1v[kk], brv.x, r10); r11 = fmaf(a1v[kk], brv.y, r11);
            }
        }
        {
            const float cz0 = czr_s[j2], cz1 = czr_s[j2 + 1];
            const float cr0 = czr_s[64 + j2], cr1 = czr_s[64 + j2 + 1];
            z00 = fast_sigmoid(z00 + cz0); z01 = fast_sigmoid(z01 + cz1);
            z10 = fast_sigmoid(z10 + cz0); z11 = fast_sigmoid(z11 + cz1);
            r00 = fast_sigmoid(r00 + cr0); r01 = fast_sigmoid(r01 + cr1);
            r10 = fast_sigmoid(r10 + cr0); r11 = fast_sigmoid(r11 + cr1);
        }
        rwR[i2 * 64 + j2] = r00 * w00;       rwR[i2 * 64 + j2 + 1] = r01 * w01;
        rwR[(i2 + 1) * 64 + j2] = r10 * w10; rwR[(i2 + 1) * 64 + j2 + 1] = r11 * w11;
        __syncthreads();
        float h00 = 0, h01 = 0, h10 = 0, h11 = 0;
        for (int k0 = 0; k0 < 64; k0 += 4) {
            const float4 a0 = *(const float4*)&rwR[i2 * 64 + k0];
            const float4 a1 = *(const float4*)&rwR[(i2 + 1) * 64 + k0];
            const float a0v[4] = {a0.x, a0.y, a0.z, a0.w};
            const float a1v[4] = {a1.x, a1.y, a1.z, a1.w};
#pragma unroll
            for (int kk = 0; kk < 4; ++kk) {
                const float2 bhv = *(const float2*)&WhB[(k0 + kk) * 64 + j2];
                h00 = fmaf(a0v[kk], bhv.x, h00); h01 = fmaf(a0v[kk], bhv.y, h01);
                h10 = fmaf(a1v[kk], bhv.x, h10); h11 = fmaf(a1v[kk], bhv.y, h11);
            }
        }
        {
            const float ch0 = czr_s[128 + j2], ch1 = czr_s[128 + j2 + 1];
            h00 = fast_tanh(h00 + ch0); h01 = fast_tanh(h01 + ch1);
            h10 = fast_tanh(h10 + ch0); h11 = fast_tanh(h11 + ch1);
        }
        w00 = z00 * w00 + (1.f - z00) * h00;
        w01 = z01 * w01 + (1.f - z01) * h01;
        w10 = z10 * w10 + (1.f - z10) * h10;
        w11 = z11 * w11 + (1.f - z11) * h11;
        {
            const float wo0 = wo_s[j2], wo1 = wo_s[j2 + 1];
            float vp0 = w00 * wo0 + w01 * wo1;
            float vp1 = w10 * wo0 + w11 * wo1;
            vp0 += __shfl_xor(vp0, 1);  vp1 += __shfl_xor(vp1, 1);
            vp0 += __shfl_xor(vp0, 2);  vp1 += __shfl_xor(vp1, 2);
            vp0 += __shfl_xor(vp0, 4);  vp1 += __shfl_xor(vp1, 4);
            vp0 += __shfl_xor(vp0, 8);  vp1 += __shfl_xor(vp1, 8);
            vp0 += __shfl_xor(vp0, 16); vp1 += __shfl_xor(vp1, 16);
            if ((tid & 31) == 0) {
                v_out[t * 64 + i2]     = vp0;
                v_out[t * 64 + i2 + 1] = vp1;
            }
        }
        wR[i2 * 64 + j2] = w00;       wR[i2 * 64 + j2 + 1] = w01;
        wR[(i2 + 1) * 64 + j2] = w10; wR[(i2 + 1) * 64 + j2 + 1] = w11;
        __syncthreads();
    }
    w_final[i2 * 64 + j2] = w00;       w_final[i2 * 64 + j2 + 1] = w01;
    w_final[(i2 + 1) * 64 + j2] = w10; w_final[(i2 + 1) * 64 + j2 + 1] = w11;
}

__global__ __launch_bounds__(256) void smatvec_kernel(const float* __restrict__ x,
                                                      const float* __restrict__ v,
                                                      float* __restrict__ s) {
    const int t = blockIdx.y;
    const int tid = threadIdx.x;
    const int l4 = tid & 3;
    const int rloc = tid >> 2;
    __shared__ float vs[64];
    if (tid < 64) vs[tid] = v[t * 64 + tid];
    __syncthreads();
    const int row = blockIdx.x * 64 + rloc;
    if (row < N_NODES) {
        const float4* xr = (const float4*)(x + ((size_t)t * N_NODES + row) * D);
        float acc = 0.f;
#pragma unroll
        for (int i = 0; i < 4; ++i) {
            const int c = i * 4 + l4;
            const float4 xv = xr[c];
            acc += xv.x * vs[c * 4 + 0] + xv.y * vs[c * 4 + 1] +
                   xv.z * vs[c * 4 + 2] + xv.w * vs[c * 4 + 3];
        }
        acc += __shfl_xor(acc, 1);
        acc += __shfl_xor(acc, 2);
        if (l4 == 0) s[(size_t)t * N_NODES + row] = acc;
    }
}

// ---------- fast path: hist -> scan -> sort-scatter -> accumulate ----------

__global__ __launch_bounds__(256) void hist_kernel(const int* __restrict__ dst,
                                                   unsigned* __restrict__ hist) {
    const int t = blockIdx.y;
    const int tid = threadIdx.x;
    __shared__ unsigned h[256];
    h[tid] = 0;
    __syncthreads();
    const int4* dp = (const int4*)(dst + (size_t)t * N_EDGES);
    const int base = blockIdx.x * 4096 + tid;
#pragma unroll
    for (int it = 0; it < 16; ++it) {
        const int i4 = base + it * 256;
        if (i4 < N_E4) {
            const int4 d = dp[i4];
            atomicAdd(&h[d.x >> BKT_BITS], 1u);
            atomicAdd(&h[d.y >> BKT_BITS], 1u);
            atomicAdd(&h[d.z >> BKT_BITS], 1u);
            atomicAdd(&h[d.w >> BKT_BITS], 1u);
        }
    }
    __syncthreads();
    if (h[tid]) atomicAdd(&hist[t * 256 + tid], h[tid]);
}

__global__ __launch_bounds__(256) void scan_kernel(const unsigned* __restrict__ hist,
                                                   unsigned* __restrict__ start,
                                                   unsigned* __restrict__ cursor) {
    __shared__ unsigned sc[256];
    const int tid = threadIdx.x;
    for (int t = 0; t < T_STEPS; ++t) {
        const unsigned c = hist[t * 256 + tid];
        unsigned v = c;
        sc[tid] = v;
        __syncthreads();
        for (int off = 1; off < 256; off <<= 1) {
            const unsigned add = (tid >= off) ? sc[tid - off] : 0u;
            __syncthreads();
            v += add;
            sc[tid] = v;
            __syncthreads();
        }
        const unsigned st = (unsigned)(t * N_EDGES) + (v - c);
        start[t * 256 + tid] = st;
        cursor[t * 256 + tid] = st;
        __syncthreads();
    }
}

// Block-sorted scatter: counting-sort 8192 edges in LDS, then write records
// bucket-contiguously (coalesced runs) into global bucket regions.
__global__ __launch_bounds__(1024) void scatter_sort_kernel(
    const int* __restrict__ src, const int* __restrict__ dst,
    const float* __restrict__ s, unsigned* __restrict__ cursor,
    unsigned* __restrict__ recs) {
    const int t = blockIdx.y;
    const int tid = threadIdx.x;
    __shared__ unsigned recL[SC_EPB];
    __shared__ unsigned char bktL[SC_EPB];
    __shared__ unsigned bh[256];     // block histogram
    __shared__ unsigned sc[256];     // inclusive scan
    __shared__ unsigned lofs[256];   // running local offset (starts at excl scan)
    __shared__ unsigned badj[256];   // global_base - local_base

    if (tid < 256) bh[tid] = 0;
    __syncthreads();

    const int4* sp = (const int4*)(src + (size_t)t * N_EDGES);
    const int4* dp = (const int4*)(dst + (size_t)t * N_EDGES);
    const float* st = s + (size_t)t * N_NODES;

    unsigned rec[8];
    int bkt[8];
#pragma unroll
    for (int k = 0; k < 8; ++k) bkt[k] = -1;

    const int i4base = blockIdx.x * SC_I4 + tid;
#pragma unroll
    for (int it = 0; it < 2; ++it) {
        const int i4 = i4base + it * 1024;
        if (i4 < N_E4) {
            const int4 sv = sp[i4];
            const int4 dv = dp[i4];
            const int ss[4] = {sv.x, sv.y, sv.z, sv.w};
            const int dd[4] = {dv.x, dv.y, dv.z, dv.w};
#pragma unroll
            for (int j = 0; j < 4; ++j) {
                const int q = (int)llrintf(st[ss[j]] * QSCALE);
                const int b = dd[j] >> BKT_BITS;
                rec[it * 4 + j] = ((unsigned)(dd[j] & (BKT_SIZE - 1)) << 22) |
                                  ((unsigned)q & 0x3FFFFFu);
                bkt[it * 4 + j] = b;
                atomicAdd(&bh[b], 1u);
            }
        }
    }
    __syncthreads();
    // exclusive scan of bh over 256 entries (first 256 threads; all sync)
    if (tid < 256) sc[tid] = bh[tid];
    __syncthreads();
    for (int off = 1; off < 256; off <<= 1) {
        unsigned add = 0;
        if (tid < 256 && tid >= off) add = sc[tid - off];
        __syncthreads();
        if (tid < 256) sc[tid] += add;
        __syncthreads();
    }
    if (tid < 256) {
        const unsigned cnt = bh[tid];
        const unsigned ex = sc[tid] - cnt;
        lofs[tid] = ex;
        unsigned gb = 0;
        if (cnt) gb = atomicAdd(&cursor[t * 256 + tid], cnt);
        badj[tid] = gb - ex;   // wraps ok (mod 2^32)
    }
    __syncthreads();
    // reorder into LDS sorted by bucket
#pragma unroll
    for (int k = 0; k < 8; ++k) {
        if (bkt[k] >= 0) {
            const unsigned pos = atomicAdd(&lofs[bkt[k]], 1u);
            recL[pos] = rec[k];
            bktL[pos] = (unsigned char)bkt[k];
        }
    }
    __syncthreads();
    // coalesced-ish writeout: consecutive i -> consecutive global within bucket
    const int nrec = min(SC_EPB, N_EDGES - blockIdx.x * SC_EPB);
    for (int i = tid; i < nrec; i += 1024) {
        const unsigned b = bktL[i];
        recs[badj[b] + (unsigned)i] = recL[i];
    }
}

__global__ __launch_bounds__(256) void accum_kernel(const unsigned* __restrict__ recs,
                                                    const unsigned* __restrict__ start,
                                                    const float* __restrict__ bo,
                                                    float* __restrict__ out) {
    const int b = blockIdx.x;
    const int t = blockIdx.y;
    const int tid = threadIdx.x;
    __shared__ unsigned long long bins[BKT_SIZE];
    bins[tid] = 0ULL;
    bins[tid + 256] = 0ULL;
    __syncthreads();
    const unsigned s0 = start[t * 256 + b];
    const unsigned s1 = start[t * 256 + b + 1];
    for (unsigned i = s0 + tid; i < s1; i += 256) {
        const unsigned rec = recs[i];
        const unsigned dl = rec >> 22;
        const long long q = (long long)(((int)(rec << 10)) >> 10);
        atomicAdd(&bins[dl], (unsigned long long)((1ULL << 41) + (unsigned long long)q));
    }
    __syncthreads();
    const float bo0 = bo[0];
#pragma unroll
    for (int k = 0; k < 2; ++k) {
        const int i = tid + k * 256;
        const int node = b * BKT_SIZE + i;
        if (node < N_NODES) {
            const unsigned long long tot = bins[i];
            const unsigned long long deg = (tot + (1ULL << 40)) >> 41;
            const long long rem = (long long)(tot - (deg << 41));
            const float acc = (float)rem * QINV;
            out[(size_t)t * N_NODES + node] = bo0 + acc / fmaxf((float)deg, 1.f);
        }
    }
}

// ---------- fallback path (round-2 proven): packed global atomics ----------

__global__ __launch_bounds__(256) void edge_kernel(const int* __restrict__ src,
                                                   const int* __restrict__ dst,
                                                   const float* __restrict__ s,
                                                   unsigned long long* __restrict__ packed) {
    const int t = blockIdx.y;
    const int e4 = blockIdx.x * 256 + threadIdx.x;
    if (e4 * 4 >= N_EDGES) return;
    const int4* sp = (const int4*)(src + (size_t)t * N_EDGES);
    const int4* dp = (const int4*)(dst + (size_t)t * N_EDGES);
    const float* st = s + (size_t)t * N_NODES;
    unsigned long long* pk = packed + (size_t)t * N_NODES;
    const int4 s4 = sp[e4];
    const int4 d4 = dp[e4];
    const float v0 = st[s4.x], v1 = st[s4.y], v2 = st[s4.z], v3 = st[s4.w];
    const unsigned long long base = 1ULL << 41;
    atomicAdd(&pk[d4.x], base + (unsigned long long)(long long)llrintf(v0 * PACK_SCALE));
    atomicAdd(&pk[d4.y], base + (unsigned long long)(long long)llrintf(v1 * PACK_SCALE));
    atomicAdd(&pk[d4.z], base + (unsigned long long)(long long)llrintf(v2 * PACK_SCALE));
    atomicAdd(&pk[d4.w], base + (unsigned long long)(long long)llrintf(v3 * PACK_SCALE));
}

__global__ __launch_bounds__(256) void out_kernel(const unsigned long long* __restrict__ packed,
                                                  const float* __restrict__ bo,
                                                  float* __restrict__ out) {
    const int i = blockIdx.x * 256 + threadIdx.x;
    if (i < T_STEPS * N_NODES) {
        const unsigned long long tot = packed[i];
        const unsigned long long deg = (tot + (1ULL << 40)) >> 41;
        const long long rem = (long long)(tot - (deg << 41));
        const float acc = (float)rem * PACK_INV;
        out[i] = bo[0] + acc / fmaxf((float)deg, 1.0f);
    }
}

extern "C" void kernel_launch(void* const* d_in, const int* in_sizes, int n_in,
                              void* d_out, int out_size, void* d_ws, size_t ws_size,
                              hipStream_t stream) {
    const float* x  = (const float*)d_in[0];
    const int* src  = (const int*)d_in[1];
    const int* dst  = (const int*)d_in[2];
    const float* iw = (const float*)d_in[3];
    const float* Wz = (const float*)d_in[4];
    const float* bz = (const float*)d_in[5];
    const float* Wr = (const float*)d_in[6];
    const float* br = (const float*)d_in[7];
    const float* Wh = (const float*)d_in[8];
    const float* bh = (const float*)d_in[9];
    const float* Wp = (const float*)d_in[10];
    const float* bp = (const float*)d_in[11];
    const float* Wo = (const float*)d_in[12];
    const float* bo = (const float*)d_in[13];
    float* out = (float*)d_out;   // [3*N outs][64*64 w_final]
    float* ws  = (float*)d_ws;

    const size_t FAST_NEED = (size_t)5102688 * sizeof(float);
    if (ws_size >= FAST_NEED) {
        float* colsum = ws;                                   // 192 f
        float* vbuf   = ws + 192;                             // 192 f
        float* sbuf   = ws + 384;                             // 300000 f
        unsigned* hist   = (unsigned*)(ws + 300384);          // 768 u32
        unsigned* bstart = (unsigned*)(ws + 301152);          // 768 u32
        unsigned* cursor = (unsigned*)(ws + 301920);          // 768 u32
        unsigned* recs   = (unsigned*)(ws + 302688);          // 4.8M u32

        hipMemsetAsync(colsum, 0, 192 * sizeof(float), stream);
        hipMemsetAsync(hist, 0, 768 * sizeof(unsigned), stream);

        colsum_kernel<<<dim3(782, 3), 256, 0, stream>>>(x, colsum);
        gru1024_kernel<<<1, 1024, 0, stream>>>(colsum, iw, Wz, bz, Wr, br, Wh, bh,
                                               Wp, bp, Wo, vbuf,
                                               out + (size_t)T_STEPS * N_NODES);
        hist_kernel<<<dim3(98, 3), 256, 0, stream>>>(dst, hist);
        scan_kernel<<<1, 256, 0, stream>>>(hist, bstart, cursor);
        smatvec_kernel<<<dim3(1563, 3), 256, 0, stream>>>(x, vbuf, sbuf);
        scatter_sort_kernel<<<dim3(SC_BLOCKS, 3), 1024, 0, stream>>>(src, dst, sbuf,
                                                                     cursor, recs);
        accum_kernel<<<dim3(NBKT, 3), 256, 0, stream>>>(recs, bstart, bo, out);
    } else {
        float* colsum = ws;
        unsigned long long* packed = (unsigned long long*)(ws + 192);
        float* vbuf   = ws + 600192;
        float* sbuf   = ws + 600384;

        hipMemsetAsync(ws, 0, (size_t)600192 * sizeof(float), stream);

        colsum_kernel<<<dim3(782, 3), 256, 0, stream>>>(x, colsum);
        gru1024_kernel<<<1, 1024, 0, stream>>>(colsum, iw, Wz, bz, Wr, br, Wh, bh,
                                               Wp, bp, Wo, vbuf,
                                               out + (size_t)T_STEPS * N_NODES);
        smatvec_kernel<<<dim3(1563, 3), 256, 0, stream>>>(x, vbuf, sbuf);
        edge_kernel<<<dim3(1563, 3), 256, 0, stream>>>(src, dst, sbuf, packed);
        out_kernel<<<1172, 256, 0, stream>>>(packed, bo, out);
    }
}